// Round 6
// baseline (68.389 us; speedup 1.0000x reference)
//
#include <hip/hip_runtime.h>
#include <hip/hip_bf16.h>

#define N_ATOMS   200000
#define D_IN      256
#define D_OUT     256
#define N_SPECIES 4
#define N_STRUCT  2000
#define M_PAD     2048      // padded struct rows for GEMM tiling
#define KFLAT     1024      // N_SPECIES * D_IN

typedef __attribute__((ext_vector_type(8))) short bf16x8;
typedef __attribute__((ext_vector_type(4))) float f32x4;

__device__ inline unsigned short f2bf(float f) {
    unsigned int u = __float_as_uint(f);
    unsigned int r = (u + 0x7fffu + ((u >> 16) & 1u)) >> 16;   // RNE
    return (unsigned short)r;
}

// ---- ws layout (bytes) ----
// 0        : Wt  bf16 [16][256][64]   = 524288   (kbg = s*4 + (k>>6), [n][k'] per block)
// 524288   : S   bf16 [2048][1024]    = 4194304  (rows >= 2000 stay poison, never stored)
// 4718592  : cnt f32  [2048][4]       = 32768

// K1: convert + transpose W -> Wt[kbg][n][kp]
__global__ void k_wt(const float* __restrict__ W, unsigned short* __restrict__ Wt) {
    int k = blockIdx.x;        // 0..255
    int n = threadIdx.x;       // 0..255
    for (int s = 0; s < N_SPECIES; ++s) {
        float v = W[((size_t)s * 256 + k) * 256 + n];
        Wt[(((size_t)(s * 4 + (k >> 6)) * 256 + n) * 64) + (k & 63)] = f2bf(v);
    }
}

// 64-ary lower_bound over sorted sidx (whole wave participates)
__device__ __forceinline__ int lb64(const int* __restrict__ sidx, int key, int lane) {
    int lo = 0, hi = N_ATOMS;
    while (hi - lo > 64) {
        int step = (hi - lo + 63) >> 6;
        int pos  = lo + lane * step;
        int v    = (pos < hi) ? sidx[pos] : 0x7fffffff;
        unsigned long long m = __ballot(v < key);
        int c = __popcll(m);
        int nlo = (c == 0)  ? lo : (lo + (c - 1) * step + 1);
        int nhi = (c == 64) ? hi : min(hi, lo + c * step);
        lo = nlo; hi = nhi;
    }
    int pos = lo + lane;
    int v   = (pos < hi) ? sidx[pos] : 0x7fffffff;
    unsigned long long m = __ballot(v < key);
    return lo + __popcll(m);
}

// K2: ONE WAVE = ONE STRUCTURE. No LDS, no barriers. Depth-4 named-register
// prefetch over the structure's contiguous rows; species switch wave-uniform;
// single non-atomic bf16 write of S[g] + cnt[g].
__global__ __launch_bounds__(256) void k_seg3(
        const float* __restrict__ x, const int* __restrict__ spec,
        const int* __restrict__ sidx, unsigned short* __restrict__ S,
        float* __restrict__ cnt) {

    int t = threadIdx.x, w = t >> 6, lane = t & 63;
    int g = blockIdx.x * 4 + w;
    if (g >= N_STRUCT) return;

    int s0 = lb64(sidx, g,     lane);
    int s1 = lb64(sidx, g + 1, lane);
    int n  = s1 - s0;

    f32x4 a0 = (f32x4){0.f,0.f,0.f,0.f}, a1 = a0, a2 = a0, a3 = a0;
    float c0 = 0.f, c1 = 0.f, c2 = 0.f, c3 = 0.f;

    if (n > 0) {
        const float* xb = x + (size_t)s0 * 256 + lane * 4;
        const int*   qb = spec + s0;
        int nm1 = n - 1;

#define LDX(idx) (*(const f32x4*)(xb + (size_t)min(idx, nm1) * 256))
#define LDQ(idx) (qb[min(idx, nm1)])
#define CONS(vv, qq)                                                      \
        { int sp = __builtin_amdgcn_readfirstlane(qq);                    \
          switch (sp) {                                                   \
              case 0: a0 += vv; c0 += 1.f; break;                         \
              case 1: a1 += vv; c1 += 1.f; break;                         \
              case 2: a2 += vv; c2 += 1.f; break;                         \
              default: a3 += vv; c3 += 1.f; break; } }

        f32x4 v0 = LDX(0); int q0 = LDQ(0);
        f32x4 v1 = LDX(1); int q1 = LDQ(1);
        f32x4 v2 = LDX(2); int q2 = LDQ(2);
        f32x4 v3 = LDX(3); int q3 = LDQ(3);

        for (int r = 0; r < n; r += 4) {
            CONS(v0, q0);
            v0 = LDX(r + 4); q0 = LDQ(r + 4);
            if (r + 1 < n) CONS(v1, q1);
            v1 = LDX(r + 5); q1 = LDQ(r + 5);
            if (r + 2 < n) CONS(v2, q2);
            v2 = LDX(r + 6); q2 = LDQ(r + 6);
            if (r + 3 < n) CONS(v3, q3);
            v3 = LDX(r + 7); q3 = LDQ(r + 7);
        }
#undef LDX
#undef LDQ
#undef CONS
    }

    unsigned short* Sg = S + (size_t)g * KFLAT + lane * 4;
    ushort4 u;
    u.x = f2bf(a0[0]); u.y = f2bf(a0[1]); u.z = f2bf(a0[2]); u.w = f2bf(a0[3]);
    *(ushort4*)(Sg + 0)   = u;
    u.x = f2bf(a1[0]); u.y = f2bf(a1[1]); u.z = f2bf(a1[2]); u.w = f2bf(a1[3]);
    *(ushort4*)(Sg + 256) = u;
    u.x = f2bf(a2[0]); u.y = f2bf(a2[1]); u.z = f2bf(a2[2]); u.w = f2bf(a2[3]);
    *(ushort4*)(Sg + 512) = u;
    u.x = f2bf(a3[0]); u.y = f2bf(a3[1]); u.z = f2bf(a3[2]); u.w = f2bf(a3[3]);
    *(ushort4*)(Sg + 768) = u;

    if (lane == 0) {
        float4 c4; c4.x = c0; c4.y = c1; c4.z = c2; c4.w = c3;
        *(float4*)(cnt + (size_t)g * 4) = c4;
    }
}

// K3: barrier-free GEMM. 128 blocks x 4 waves; each wave owns a 16x64 tile,
// A-frags direct from S (L2/L3), B-frags direct from Wt (L2). No LDS.
__global__ __launch_bounds__(256) void k_gemm3(
        const unsigned short* __restrict__ S, const float* __restrict__ cnt,
        const float* __restrict__ b, const unsigned short* __restrict__ Wt,
        float* __restrict__ out) {

    int t = threadIdx.x, nt = t >> 6, lane = t & 63;
    int l15 = lane & 15, l4 = lane >> 4;
    int g0 = blockIdx.x * 16;

    f32x4 acc[4];
#pragma unroll
    for (int n = 0; n < 4; ++n) acc[n] = (f32x4){0.f, 0.f, 0.f, 0.f};

    const unsigned short* arow = S + (size_t)(g0 + l15) * KFLAT + l4 * 8;

#pragma unroll 4
    for (int kbg = 0; kbg < 16; ++kbg) {
        const unsigned short* wkb = Wt + (size_t)kbg * 16384 + l4 * 8;
#pragma unroll
        for (int ks = 0; ks < 2; ++ks) {
            bf16x8 af = *(const bf16x8*)(arow + kbg * 64 + ks * 32);
#pragma unroll
            for (int n = 0; n < 4; ++n) {
                bf16x8 bfr = *(const bf16x8*)(wkb + (size_t)(nt * 64 + n * 16 + l15) * 64 + ks * 32);
                acc[n] = __builtin_amdgcn_mfma_f32_16x16x32_bf16(af, bfr, acc[n], 0, 0, 0);
            }
        }
    }

    float bv[4][4];
#pragma unroll
    for (int n = 0; n < 4; ++n) {
        int col = nt * 64 + n * 16 + l15;
#pragma unroll
        for (int s = 0; s < 4; ++s) bv[n][s] = b[s * 256 + col];
    }

#pragma unroll
    for (int r = 0; r < 4; ++r) {
        int grow = g0 + l4 * 4 + r;
        if (grow < N_STRUCT) {
            float4 c4 = *(const float4*)(cnt + (size_t)grow * 4);
#pragma unroll
            for (int n = 0; n < 4; ++n) {
                int col = nt * 64 + n * 16 + l15;
                out[(size_t)grow * 256 + col] =
                    acc[n][r] + c4.x * bv[n][0] + c4.y * bv[n][1]
                              + c4.z * bv[n][2] + c4.w * bv[n][3];
            }
        }
    }
}

extern "C" void kernel_launch(void* const* d_in, const int* in_sizes, int n_in,
                              void* d_out, int out_size, void* d_ws, size_t ws_size,
                              hipStream_t stream) {
    const float* x    = (const float*)d_in[0];
    const float* W    = (const float*)d_in[1];
    const float* b    = (const float*)d_in[2];
    const int* spec   = (const int*)d_in[3];
    const int* sidx   = (const int*)d_in[4];
    float* out        = (float*)d_out;

    char* ws = (char*)d_ws;
    unsigned short* Wt = (unsigned short*)ws;               // 524288 B
    unsigned short* S  = (unsigned short*)(ws + 524288);    // 4194304 B
    float* cnt  = (float*)(ws + 4718592);                   // 32768 B

    k_wt   <<<256, 256, 0, stream>>>(W, Wt);
    k_seg3 <<<(N_STRUCT + 3) / 4, 256, 0, stream>>>(x, spec, sidx, S, cnt);
    k_gemm3<<<M_PAD / 16, 256, 0, stream>>>(S, cnt, b, Wt, out);
}